// Round 10
// baseline (76.813 us; speedup 1.0000x reference)
//
#include <hip/hip_runtime.h>
#include <hip/hip_bf16.h>

#define DMODEL 1024
#define DH 64
#define BB 4
#define SS 2048
#define NROW (BB * SS)   // 8192
#define NS 8             // kv-splits per q-tile

typedef __attribute__((ext_vector_type(8))) short bf16x8;
typedef __attribute__((ext_vector_type(4))) float f32x4;

__device__ __forceinline__ unsigned short f2bf(float f) {
    __hip_bfloat16 h = __float2bfloat16(f);
    return __builtin_bit_cast(unsigned short, h);
}

// ---------------- prep: Wt[192][1024] bf16 = [Wq|Wk|Wv]^T ----------------
__global__ __launch_bounds__(256) void prep_wt_kernel(
    const float* __restrict__ Wq, const float* __restrict__ Wk,
    const float* __restrict__ Wv, unsigned short* __restrict__ Wt)
{
    int idx = blockIdx.x * 256 + threadIdx.x;      // 0 .. 196607
    int m   = idx >> 16;                           // 0..2
    int rem = idx & 65535;
    int k   = rem >> 6;
    int n   = rem & 63;
    const float* W = (m == 0) ? Wq : (m == 1) ? Wk : Wv;
    float v = W[(size_t)k * DH + n];               // coalesced read
    Wt[(size_t)(m * 64 + n) * DMODEL + k] = f2bf(v);
}

// ---------------- QKV projection via MFMA ----------------
// 16 rows x 192 cols per block; 4 waves, wave w -> cols 48w..48w+47.
// BK=128 per step, 8 steps, ONE barrier/step; dbuf LDS for A; 2-deep A reg
// prefetch; B fragments register-prefetched one step ahead (12 uint4).
__global__ __launch_bounds__(256) void qkv_proj_mfma(
    const float* __restrict__ emb, const unsigned short* __restrict__ Wt,
    const float* __restrict__ bq, const float* __restrict__ bk,
    const float* __restrict__ bv,
    unsigned short* __restrict__ Q, unsigned short* __restrict__ K,
    unsigned short* __restrict__ V)
{
    __shared__ unsigned short A_lds[2][16][136];

    const int tid  = threadIdx.x;
    const int lane = tid & 63;
    const int w    = tid >> 6;          // wave 0..3
    const int c    = lane & 15;
    const int g    = lane >> 4;         // 0..3
    const int row0 = blockIdx.x * 16;

    f32x4 acc[3];
    #pragma unroll
    for (int t = 0; t < 3; ++t) acc[t] = (f32x4){0.f, 0.f, 0.f, 0.f};

    // A staging: 16 rows x 128 floats per step; thread -> (sr, f4 cols sc4, sc4+16)
    const int sr  = tid >> 4;
    const int sc4 = tid & 15;
    const float* src = emb + (size_t)(row0 + sr) * DMODEL + sc4 * 4;

    // 2-deep A prefetch: even tiles (0,2,4,6) in eEv*, odd (1,3,5,7) in eOd*
    float4 eEv0 = *reinterpret_cast<const float4*>(src);
    float4 eEv1 = *reinterpret_cast<const float4*>(src + 64);
    float4 eOd0 = *reinterpret_cast<const float4*>(src + 128);
    float4 eOd1 = *reinterpret_cast<const float4*>(src + 192);

    const unsigned short* brow_base = Wt + (size_t)(48 * w + c) * DMODEL + 8 * g;

    // B prefetch buffers: [t][kp] for one 128-wide K step
    uint4 bA[3][4], bB[3][4];
    #pragma unroll
    for (int t = 0; t < 3; ++t)
        #pragma unroll
        for (int kp = 0; kp < 4; ++kp)
            bA[t][kp] = *reinterpret_cast<const uint4*>(
                brow_base + (size_t)(16 * t) * DMODEL + 32 * kp);

    for (int kk = 0; kk < 4; ++kk) {
        const int ksE = 2 * kk;           // even 128-tile index
        // ===== even step: LDS buf0, A regs eEv, B regs bA =====
        {
            const int k0 = ksE * 128;
            uint2 p0, p1;
            p0.x = (unsigned)f2bf(eEv0.x) | ((unsigned)f2bf(eEv0.y) << 16);
            p0.y = (unsigned)f2bf(eEv0.z) | ((unsigned)f2bf(eEv0.w) << 16);
            p1.x = (unsigned)f2bf(eEv1.x) | ((unsigned)f2bf(eEv1.y) << 16);
            p1.y = (unsigned)f2bf(eEv1.z) | ((unsigned)f2bf(eEv1.w) << 16);
            *reinterpret_cast<uint2*>(&A_lds[0][sr][sc4 * 4])      = p0;
            *reinterpret_cast<uint2*>(&A_lds[0][sr][64 + sc4 * 4]) = p1;
            if (ksE + 2 < 8) {
                eEv0 = *reinterpret_cast<const float4*>(src + (ksE + 2) * 128);
                eEv1 = *reinterpret_cast<const float4*>(src + (ksE + 2) * 128 + 64);
            }
            __syncthreads();
            bf16x8 a[4];
            #pragma unroll
            for (int kp = 0; kp < 4; ++kp)
                a[kp] = __builtin_bit_cast(bf16x8,
                    *reinterpret_cast<const uint4*>(&A_lds[0][c][32 * kp + 8 * g]));
            // prefetch B for the odd step
            #pragma unroll
            for (int t = 0; t < 3; ++t)
                #pragma unroll
                for (int kp = 0; kp < 4; ++kp)
                    bB[t][kp] = *reinterpret_cast<const uint4*>(
                        brow_base + (size_t)(16 * t) * DMODEL + k0 + 128 + 32 * kp);
            #pragma unroll
            for (int t = 0; t < 3; ++t)
                #pragma unroll
                for (int kp = 0; kp < 4; ++kp)
                    acc[t] = __builtin_amdgcn_mfma_f32_16x16x32_bf16(
                        a[kp], __builtin_bit_cast(bf16x8, bA[t][kp]), acc[t], 0, 0, 0);
        }
        // ===== odd step: LDS buf1, A regs eOd, B regs bB =====
        {
            const int k0 = (ksE + 1) * 128;
            uint2 p0, p1;
            p0.x = (unsigned)f2bf(eOd0.x) | ((unsigned)f2bf(eOd0.y) << 16);
            p0.y = (unsigned)f2bf(eOd0.z) | ((unsigned)f2bf(eOd0.w) << 16);
            p1.x = (unsigned)f2bf(eOd1.x) | ((unsigned)f2bf(eOd1.y) << 16);
            p1.y = (unsigned)f2bf(eOd1.z) | ((unsigned)f2bf(eOd1.w) << 16);
            *reinterpret_cast<uint2*>(&A_lds[1][sr][sc4 * 4])      = p0;
            *reinterpret_cast<uint2*>(&A_lds[1][sr][64 + sc4 * 4]) = p1;
            if (ksE + 3 < 8) {
                eOd0 = *reinterpret_cast<const float4*>(src + (ksE + 3) * 128);
                eOd1 = *reinterpret_cast<const float4*>(src + (ksE + 3) * 128 + 64);
            }
            __syncthreads();
            bf16x8 a[4];
            #pragma unroll
            for (int kp = 0; kp < 4; ++kp)
                a[kp] = __builtin_bit_cast(bf16x8,
                    *reinterpret_cast<const uint4*>(&A_lds[1][c][32 * kp + 8 * g]));
            // prefetch B for the next even step
            if (ksE + 2 < 8) {
                #pragma unroll
                for (int t = 0; t < 3; ++t)
                    #pragma unroll
                    for (int kp = 0; kp < 4; ++kp)
                        bA[t][kp] = *reinterpret_cast<const uint4*>(
                            brow_base + (size_t)(16 * t) * DMODEL + k0 + 128 + 32 * kp);
            }
            #pragma unroll
            for (int t = 0; t < 3; ++t)
                #pragma unroll
                for (int kp = 0; kp < 4; ++kp)
                    acc[t] = __builtin_amdgcn_mfma_f32_16x16x32_bf16(
                        a[kp], __builtin_bit_cast(bf16x8, bB[t][kp]), acc[t], 0, 0, 0);
        }
    }

    // epilogue: bias (+ 1/8 scale folded into Q), store bf16
    #pragma unroll
    for (int t = 0; t < 3; ++t) {
        const int col = 48 * w + 16 * t + c;
        const int m   = col >> 6;
        const int lc  = col & 63;
        const float* bias = (m == 0) ? bq : (m == 1) ? bk : bv;
        unsigned short* O = (m == 0) ? Q : (m == 1) ? K : V;
        const float bs    = bias[lc];
        const float scale = (m == 0) ? 0.125f : 1.0f;
        #pragma unroll
        for (int i = 0; i < 4; ++i) {
            const int r = row0 + 4 * g + i;
            O[(size_t)r * DH + lc] = f2bf((acc[t][i] + bs) * scale);
        }
    }
}

// ---------------- causal flash attention via MFMA, KV-split ----------------
// Double-buffered K/V LDS; loads for tile kt+1 issue BEFORE tile kt's compute,
// ds-writes land after compute (async-STAGE split). One barrier per tile.
__global__ __launch_bounds__(256) void attn_mfma_split(
    const unsigned short* __restrict__ Q, const unsigned short* __restrict__ K,
    const unsigned short* __restrict__ V,
    float* __restrict__ Opart, float* __restrict__ mpart,
    float* __restrict__ lpart)
{
    __shared__ unsigned short Ks[2][64][72];   // [buf][kv][d]
    __shared__ unsigned short Vt[2][64][72];   // [buf][d][kv] (transposed)
    __shared__ unsigned short Ps[4][16][72];   // per-wave P tile [qrow][kv]

    const int tid  = threadIdx.x;
    const int lane = tid & 63;
    const int w    = tid >> 6;
    const int c    = lane & 15;
    const int g    = lane >> 4;
    const int qt   = blockIdx.x;
    const int b    = blockIdx.y;
    const int sp   = blockIdx.z;
    const int q0   = qt * 64;

    const int ntile = qt + 1;
    const int kt0 = (ntile * sp) / NS;
    const int kt1 = (ntile * (sp + 1)) / NS;

    const unsigned short* Qb = Q + (size_t)b * SS * DH;
    const unsigned short* Kb = K + (size_t)b * SS * DH;
    const unsigned short* Vb = V + (size_t)b * SS * DH;

    // Q fragments, register resident (scale 1/8 already folded in)
    bf16x8 qa[2];
    #pragma unroll
    for (int kp = 0; kp < 2; ++kp)
        qa[kp] = __builtin_bit_cast(bf16x8,
            *reinterpret_cast<const uint4*>(
                &Qb[(size_t)(q0 + 16 * w + c) * DH + 32 * kp + 8 * g]));

    f32x4 o[4];
    #pragma unroll
    for (int t = 0; t < 4; ++t) o[t] = (f32x4){0.f, 0.f, 0.f, 0.f};
    float m_i[4] = {-1e30f, -1e30f, -1e30f, -1e30f};
    float l_i[4] = {0.f, 0.f, 0.f, 0.f};

    uint4 kreg[2], vreg[2];

#define ISSUE_LOADS(KT) do {                                              \
    const int kb0_ = (KT) * 64;                                           \
    _Pragma("unroll")                                                     \
    for (int j = 0; j < 2; ++j) {                                         \
        const int idx = tid + 256 * j;                                    \
        const int kv  = idx >> 3;                                         \
        const int d0  = (idx & 7) * 8;                                    \
        kreg[j] = *reinterpret_cast<const uint4*>(                        \
            &Kb[(size_t)(kb0_ + kv) * DH + d0]);                          \
        vreg[j] = *reinterpret_cast<const uint4*>(                        \
            &Vb[(size_t)(kb0_ + kv) * DH + d0]);                          \
    }                                                                     \
} while (0)

#define WRITE_STAGE(BI) do {                                              \
    _Pragma("unroll")                                                     \
    for (int j = 0; j < 2; ++j) {                                         \
        const int idx = tid + 256 * j;                                    \
        const int kv  = idx >> 3;                                         \
        const int d0  = (idx & 7) * 8;                                    \
        *reinterpret_cast<uint4*>(&Ks[BI][kv][d0]) = kreg[j];             \
        const unsigned wd[4] = {vreg[j].x, vreg[j].y, vreg[j].z, vreg[j].w}; \
        _Pragma("unroll")                                                 \
        for (int e = 0; e < 8; ++e)                                       \
            Vt[BI][d0 + e][kv] =                                          \
                (unsigned short)(wd[e >> 1] >> (16 * (e & 1)));           \
    }                                                                     \
} while (0)

    if (kt0 < kt1) {
        ISSUE_LOADS(kt0);
        WRITE_STAGE(0);
        __syncthreads();

        for (int kt = kt0; kt < kt1; ++kt) {
            const int bi = (kt - kt0) & 1;
            const bool havenext = (kt + 1 < kt1);
            if (havenext) ISSUE_LOADS(kt + 1);   // in flight during compute

            // S = Q Ktile^T
            f32x4 s[4];
            #pragma unroll
            for (int t = 0; t < 4; ++t) s[t] = (f32x4){0.f, 0.f, 0.f, 0.f};
            __builtin_amdgcn_s_setprio(1);
            #pragma unroll
            for (int t = 0; t < 4; ++t)
                #pragma unroll
                for (int kp = 0; kp < 2; ++kp) {
                    bf16x8 kf = __builtin_bit_cast(bf16x8,
                        *reinterpret_cast<const uint4*>(
                            &Ks[bi][16 * t + c][32 * kp + 8 * g]));
                    s[t] = __builtin_amdgcn_mfma_f32_16x16x32_bf16(qa[kp], kf, s[t], 0, 0, 0);
                }
            __builtin_amdgcn_s_setprio(0);

            // causal mask (only the diagonal tile needs it)
            if (kt == qt) {
                #pragma unroll
                for (int t = 0; t < 4; ++t)
                    #pragma unroll
                    for (int i = 0; i < 4; ++i)
                        if (16 * t + c > 16 * w + 4 * g + i) s[t][i] = -1e30f;
            }

            // wave-parallel online softmax
            float al[4];
            #pragma unroll
            for (int i = 0; i < 4; ++i) {
                float v = fmaxf(fmaxf(s[0][i], s[1][i]), fmaxf(s[2][i], s[3][i]));
                v = fmaxf(v, __shfl_xor(v, 1));
                v = fmaxf(v, __shfl_xor(v, 2));
                v = fmaxf(v, __shfl_xor(v, 4));
                v = fmaxf(v, __shfl_xor(v, 8));
                const float mn = fmaxf(m_i[i], v);
                al[i] = __expf(m_i[i] - mn);
                m_i[i] = mn;
            }
            #pragma unroll
            for (int t = 0; t < 4; ++t)
                #pragma unroll
                for (int i = 0; i < 4; ++i)
                    s[t][i] = __expf(s[t][i] - m_i[i]);
            #pragma unroll
            for (int i = 0; i < 4; ++i) {
                float r = s[0][i] + s[1][i] + s[2][i] + s[3][i];
                r += __shfl_xor(r, 1);
                r += __shfl_xor(r, 2);
                r += __shfl_xor(r, 4);
                r += __shfl_xor(r, 8);
                l_i[i] = l_i[i] * al[i] + r;
            }

            // P -> per-wave LDS (reshape to A-fragment layout)
            #pragma unroll
            for (int t = 0; t < 4; ++t)
                #pragma unroll
                for (int i = 0; i < 4; ++i)
                    Ps[w][4 * g + i][16 * t + c] = f2bf(s[t][i]);

            // rescale O
            #pragma unroll
            for (int t = 0; t < 4; ++t)
                #pragma unroll
                for (int i = 0; i < 4; ++i)
                    o[t][i] *= al[i];

            // O += P Vtile
            __builtin_amdgcn_s_setprio(1);
            #pragma unroll
            for (int kp = 0; kp < 2; ++kp) {
                bf16x8 pa = __builtin_bit_cast(bf16x8,
                    *reinterpret_cast<const uint4*>(&Ps[w][c][32 * kp + 8 * g]));
                #pragma unroll
                for (int t = 0; t < 4; ++t) {
                    bf16x8 vf = __builtin_bit_cast(bf16x8,
                        *reinterpret_cast<const uint4*>(
                            &Vt[bi][16 * t + c][32 * kp + 8 * g]));
                    o[t] = __builtin_amdgcn_mfma_f32_16x16x32_bf16(pa, vf, o[t], 0, 0, 0);
                }
            }
            __builtin_amdgcn_s_setprio(0);

            if (havenext) WRITE_STAGE(bi ^ 1);   // waits vmcnt here, after compute
            __syncthreads();
        }
    }

    // epilogue: unnormalized partials
    const int rowbase = b * SS + q0 + 16 * w;
    #pragma unroll
    for (int t = 0; t < 4; ++t)
        #pragma unroll
        for (int i = 0; i < 4; ++i)
            Opart[((size_t)sp * NROW + rowbase + 4 * g + i) * DH + 16 * t + c] = o[t][i];
    if (c == 0) {
        #pragma unroll
        for (int i = 0; i < 4; ++i) {
            mpart[(size_t)sp * NROW + rowbase + 4 * g + i] = m_i[i];
            lpart[(size_t)sp * NROW + rowbase + 4 * g + i] = l_i[i];
        }
    }
#undef ISSUE_LOADS
#undef WRITE_STAGE
}

// ---------------- combine partials ----------------
__global__ __launch_bounds__(256) void attn_combine(
    const float* __restrict__ Opart, const float* __restrict__ mpart,
    const float* __restrict__ lpart, float* __restrict__ out)
{
    const int idx = blockIdx.x * 256 + threadIdx.x;   // row*16 + d4
    const int row = idx >> 4;
    const int d4  = (idx & 15) * 4;

    float m[NS];
    float M = -1e30f;
    #pragma unroll
    for (int s = 0; s < NS; ++s) {
        m[s] = mpart[(size_t)s * NROW + row];
        M = fmaxf(M, m[s]);
    }
    float L = 0.f;
    float4 acc = {0.f, 0.f, 0.f, 0.f};
    #pragma unroll
    for (int s = 0; s < NS; ++s) {
        const float wgt = __expf(m[s] - M);
        L += wgt * lpart[(size_t)s * NROW + row];
        const float4 p = *reinterpret_cast<const float4*>(
            &Opart[((size_t)s * NROW + row) * DH + d4]);
        acc.x += wgt * p.x; acc.y += wgt * p.y;
        acc.z += wgt * p.z; acc.w += wgt * p.w;
    }
    const float inv = 1.f / L;
    float4 r = {acc.x * inv, acc.y * inv, acc.z * inv, acc.w * inv};
    *reinterpret_cast<float4*>(&out[(size_t)row * DH + d4]) = r;
}

extern "C" void kernel_launch(void* const* d_in, const int* in_sizes, int n_in,
                              void* d_out, int out_size, void* d_ws, size_t ws_size,
                              hipStream_t stream) {
    const float* emb = (const float*)d_in[0];
    const float* Wq  = (const float*)d_in[1];
    const float* bq  = (const float*)d_in[2];
    const float* Wk  = (const float*)d_in[3];
    const float* bk  = (const float*)d_in[4];
    const float* Wv  = (const float*)d_in[5];
    const float* bv  = (const float*)d_in[6];
    float* out = (float*)d_out;

    unsigned short* Qw = (unsigned short*)d_ws;
    unsigned short* Kw = Qw + (size_t)NROW * DH;
    unsigned short* Vw = Kw + (size_t)NROW * DH;
    unsigned short* Wt = Vw + (size_t)NROW * DH;          // 192*1024 bf16
    float* Opart = (float*)(Wt + (size_t)192 * DMODEL);   // [NS][NROW][DH] f32
    float* mpart = Opart + (size_t)NS * NROW * DH;        // [NS][NROW]
    float* lpart = mpart + (size_t)NS * NROW;             // [NS][NROW]

    hipLaunchKernelGGL(prep_wt_kernel, dim3(768), dim3(256), 0, stream,
                       Wq, Wk, Wv, Wt);
    hipLaunchKernelGGL(qkv_proj_mfma, dim3(NROW / 16), dim3(256), 0, stream,
                       emb, Wt, bq, bk, bv, Qw, Kw, Vw);
    hipLaunchKernelGGL(attn_mfma_split, dim3(SS / 64, BB, NS), dim3(256), 0, stream,
                       Qw, Kw, Vw, Opart, mpart, lpart);
    hipLaunchKernelGGL(attn_combine, dim3(NROW * 16 / 256), dim3(256), 0, stream,
                       Opart, mpart, lpart, out);
}

// Round 11
// 61.400 us; speedup vs baseline: 1.2510x; 1.2510x over previous
//
#include <hip/hip_runtime.h>
#include <hip/hip_bf16.h>

#define DMODEL 1024
#define DH 64
#define BB 4
#define SS 2048
#define NROW (BB * SS)   // 8192
#define NS 8             // kv-splits per q-tile

typedef __attribute__((ext_vector_type(8))) short bf16x8;
typedef __attribute__((ext_vector_type(4))) float f32x4;

__device__ __forceinline__ unsigned short f2bf(float f) {
    __hip_bfloat16 h = __float2bfloat16(f);
    return __builtin_bit_cast(unsigned short, h);
}

// ---------------- prep: Wt[192][1024] bf16 = [Wq|Wk|Wv]^T ----------------
__global__ __launch_bounds__(256) void prep_wt_kernel(
    const float* __restrict__ Wq, const float* __restrict__ Wk,
    const float* __restrict__ Wv, unsigned short* __restrict__ Wt)
{
    int idx = blockIdx.x * 256 + threadIdx.x;      // 0 .. 196607
    int m   = idx >> 16;                           // 0..2
    int rem = idx & 65535;
    int k   = rem >> 6;
    int n   = rem & 63;
    const float* W = (m == 0) ? Wq : (m == 1) ? Wk : Wv;
    float v = W[(size_t)k * DH + n];               // coalesced read
    Wt[(size_t)(m * 64 + n) * DMODEL + k] = f2bf(v);
}

// ---------------- QKV projection via MFMA, in-block K-split ----------------
// 512 thr = 8 waves. Tile: 16 rows x 192 cols. Waves 0-3: K [0,512) cols 48w..;
// waves 4-7: K [512,1024) same cols. 4 steps of BK=128, 1 barrier/step,
// dbuf A LDS. Epilogue: LDS-reduce high half into low half.
__global__ __launch_bounds__(512) void qkv_proj_mfma(
    const float* __restrict__ emb, const unsigned short* __restrict__ Wt,
    const float* __restrict__ bq, const float* __restrict__ bk,
    const float* __restrict__ bv,
    unsigned short* __restrict__ Q, unsigned short* __restrict__ K,
    unsigned short* __restrict__ V)
{
    __shared__ unsigned short A_lds[2][16][264];   // 16 rows x 256 k (lo|hi)
    __shared__ float Red[4][16][48];               // high-half partial C

    const int tid  = threadIdx.x;
    const int lane = tid & 63;
    const int w    = tid >> 6;          // 0..7
    const int wc   = w & 3;             // col group (48 cols)
    const int h    = w >> 2;            // K half
    const int c    = lane & 15;
    const int g    = lane >> 4;
    const int row0 = blockIdx.x * 16;

    f32x4 acc[3];
    #pragma unroll
    for (int t = 0; t < 3; ++t) acc[t] = (f32x4){0.f, 0.f, 0.f, 0.f};

    // A staging: per step 16 rows x 256 floats (lo 128 | hi 128) = 1024 float4.
    // Thread covers rows sr0 and sr0+8 at float4-col c4.
    const int sr0 = tid >> 6;                     // 0..7
    const int c4  = tid & 63;                     // 0..63
    const int gchunk = (c4 >> 5) ? 512 : 0;       // lo / hi K chunk
    const int coff   = (c4 & 31) * 4;
    const float* s0 = emb + (size_t)(row0 + sr0) * DMODEL + gchunk + coff;
    const float* s1 = emb + (size_t)(row0 + sr0 + 8) * DMODEL + gchunk + coff;

    float4 f0 = *reinterpret_cast<const float4*>(s0);
    float4 f1 = *reinterpret_cast<const float4*>(s1);

    const unsigned short* bbase =
        Wt + (size_t)(48 * wc + c) * DMODEL + h * 512 + 8 * g;

    for (int s = 0; s < 4; ++s) {
        const int buf = s & 1;
        {
            uint2 p0, p1;
            p0.x = (unsigned)f2bf(f0.x) | ((unsigned)f2bf(f0.y) << 16);
            p0.y = (unsigned)f2bf(f0.z) | ((unsigned)f2bf(f0.w) << 16);
            p1.x = (unsigned)f2bf(f1.x) | ((unsigned)f2bf(f1.y) << 16);
            p1.y = (unsigned)f2bf(f1.z) | ((unsigned)f2bf(f1.w) << 16);
            *reinterpret_cast<uint2*>(&A_lds[buf][sr0][c4 * 4])     = p0;
            *reinterpret_cast<uint2*>(&A_lds[buf][sr0 + 8][c4 * 4]) = p1;
        }
        if (s < 3) {   // loads for s+1 fly during this step's compute
            f0 = *reinterpret_cast<const float4*>(s0 + 128 * (s + 1));
            f1 = *reinterpret_cast<const float4*>(s1 + 128 * (s + 1));
        }
        __syncthreads();

        bf16x8 a[4];
        #pragma unroll
        for (int kp = 0; kp < 4; ++kp)
            a[kp] = __builtin_bit_cast(bf16x8,
                *reinterpret_cast<const uint4*>(
                    &A_lds[buf][c][128 * h + 32 * kp + 8 * g]));

        uint4 bf[3][4];
        #pragma unroll
        for (int t = 0; t < 3; ++t)
            #pragma unroll
            for (int kp = 0; kp < 4; ++kp)
                bf[t][kp] = *reinterpret_cast<const uint4*>(
                    bbase + (size_t)(16 * t) * DMODEL + 128 * s + 32 * kp);
        #pragma unroll
        for (int kp = 0; kp < 4; ++kp)
            #pragma unroll
            for (int t = 0; t < 3; ++t)
                acc[t] = __builtin_amdgcn_mfma_f32_16x16x32_bf16(
                    a[kp], __builtin_bit_cast(bf16x8, bf[t][kp]), acc[t], 0, 0, 0);
    }

    __syncthreads();
    if (h == 1) {
        #pragma unroll
        for (int t = 0; t < 3; ++t)
            #pragma unroll
            for (int i = 0; i < 4; ++i)
                Red[wc][4 * g + i][16 * t + c] = acc[t][i];
    }
    __syncthreads();
    if (h == 0) {
        #pragma unroll
        for (int t = 0; t < 3; ++t) {
            const int col = 48 * wc + 16 * t + c;
            const int m   = col >> 6;
            const int lc  = col & 63;
            const float* bias = (m == 0) ? bq : (m == 1) ? bk : bv;
            unsigned short* O = (m == 0) ? Q : (m == 1) ? K : V;
            const float bs    = bias[lc];
            const float scale = (m == 0) ? 0.125f : 1.0f;
            #pragma unroll
            for (int i = 0; i < 4; ++i) {
                const float v = acc[t][i] + Red[wc][4 * g + i][16 * t + c];
                const int r = row0 + 4 * g + i;
                O[(size_t)r * DH + lc] = f2bf((v + bs) * scale);
            }
        }
    }
}

// ---------------- causal flash attention via MFMA, KV-split ----------------
// Single-buffer LDS (r8 structure, best measured) + XOR row swizzle on Vt:
// logical row d stored at physical row d ^ ((d>>3)&7)  -> conflict-free writes.
__global__ __launch_bounds__(256) void attn_mfma_split(
    const unsigned short* __restrict__ Q, const unsigned short* __restrict__ K,
    const unsigned short* __restrict__ V,
    float* __restrict__ Opart, float* __restrict__ mpart,
    float* __restrict__ lpart)
{
    __shared__ unsigned short Ks[64][72];      // [kv][d]
    __shared__ unsigned short Vt[64][72];      // [phys_d][kv], row-swizzled
    __shared__ unsigned short Ps[4][16][72];   // per-wave P tile [qrow][kv]

    const int tid  = threadIdx.x;
    const int lane = tid & 63;
    const int w    = tid >> 6;
    const int c    = lane & 15;
    const int g    = lane >> 4;
    const int qt   = blockIdx.x;
    const int b    = blockIdx.y;
    const int sp   = blockIdx.z;
    const int q0   = qt * 64;

    const int ntile = qt + 1;
    const int kt0 = (ntile * sp) / NS;
    const int kt1 = (ntile * (sp + 1)) / NS;

    const unsigned short* Qb = Q + (size_t)b * SS * DH;
    const unsigned short* Kb = K + (size_t)b * SS * DH;
    const unsigned short* Vb = V + (size_t)b * SS * DH;

    // Q fragments, register resident (scale 1/8 already folded in)
    bf16x8 qa[2];
    #pragma unroll
    for (int kp = 0; kp < 2; ++kp)
        qa[kp] = __builtin_bit_cast(bf16x8,
            *reinterpret_cast<const uint4*>(
                &Qb[(size_t)(q0 + 16 * w + c) * DH + 32 * kp + 8 * g]));

    f32x4 o[4];
    #pragma unroll
    for (int t = 0; t < 4; ++t) o[t] = (f32x4){0.f, 0.f, 0.f, 0.f};
    float m_i[4] = {-1e30f, -1e30f, -1e30f, -1e30f};
    float l_i[4] = {0.f, 0.f, 0.f, 0.f};

    for (int kt = kt0; kt < kt1; ++kt) {
        const int kb0 = kt * 64;
        __syncthreads();   // prior tile's LDS reads done
        // stage K (row-major) and V (transposed, row-swizzled)
        #pragma unroll
        for (int j = 0; j < 2; ++j) {
            const int idx = tid + 256 * j;
            const int kv  = idx >> 3;
            const int m8  = idx & 7;
            const int d0  = m8 * 8;
            *reinterpret_cast<uint4*>(&Ks[kv][d0]) =
                *reinterpret_cast<const uint4*>(&Kb[(size_t)(kb0 + kv) * DH + d0]);
            const uint4 vv =
                *reinterpret_cast<const uint4*>(&Vb[(size_t)(kb0 + kv) * DH + d0]);
            const unsigned wd[4] = {vv.x, vv.y, vv.z, vv.w};
            #pragma unroll
            for (int e = 0; e < 8; ++e)
                Vt[(d0 + e) ^ m8][kv] =
                    (unsigned short)(wd[e >> 1] >> (16 * (e & 1)));
        }
        __syncthreads();

        // S = Q Ktile^T  (4 col-tiles x 2 k-steps)
        f32x4 s[4];
        #pragma unroll
        for (int t = 0; t < 4; ++t) s[t] = (f32x4){0.f, 0.f, 0.f, 0.f};
        #pragma unroll
        for (int t = 0; t < 4; ++t)
            #pragma unroll
            for (int kp = 0; kp < 2; ++kp) {
                bf16x8 kf = __builtin_bit_cast(bf16x8,
                    *reinterpret_cast<const uint4*>(&Ks[16 * t + c][32 * kp + 8 * g]));
                s[t] = __builtin_amdgcn_mfma_f32_16x16x32_bf16(qa[kp], kf, s[t], 0, 0, 0);
            }

        // causal mask (only the diagonal tile needs it)
        if (kt == qt) {
            #pragma unroll
            for (int t = 0; t < 4; ++t)
                #pragma unroll
                for (int i = 0; i < 4; ++i)
                    if (16 * t + c > 16 * w + 4 * g + i) s[t][i] = -1e30f;
        }

        // wave-parallel online softmax; quarter-wave owns q-rows 4g..4g+3 (i)
        float al[4];
        #pragma unroll
        for (int i = 0; i < 4; ++i) {
            float v = fmaxf(fmaxf(s[0][i], s[1][i]), fmaxf(s[2][i], s[3][i]));
            v = fmaxf(v, __shfl_xor(v, 1));
            v = fmaxf(v, __shfl_xor(v, 2));
            v = fmaxf(v, __shfl_xor(v, 4));
            v = fmaxf(v, __shfl_xor(v, 8));
            const float mn = fmaxf(m_i[i], v);
            al[i] = __expf(m_i[i] - mn);
            m_i[i] = mn;
        }
        #pragma unroll
        for (int t = 0; t < 4; ++t)
            #pragma unroll
            for (int i = 0; i < 4; ++i)
                s[t][i] = __expf(s[t][i] - m_i[i]);
        #pragma unroll
        for (int i = 0; i < 4; ++i) {
            float r = s[0][i] + s[1][i] + s[2][i] + s[3][i];
            r += __shfl_xor(r, 1);
            r += __shfl_xor(r, 2);
            r += __shfl_xor(r, 4);
            r += __shfl_xor(r, 8);
            l_i[i] = l_i[i] * al[i] + r;
        }

        // P -> per-wave LDS (reshape to A-fragment layout)
        #pragma unroll
        for (int t = 0; t < 4; ++t)
            #pragma unroll
            for (int i = 0; i < 4; ++i)
                Ps[w][4 * g + i][16 * t + c] = f2bf(s[t][i]);

        // rescale O
        #pragma unroll
        for (int t = 0; t < 4; ++t)
            #pragma unroll
            for (int i = 0; i < 4; ++i)
                o[t][i] *= al[i];

        // O += P Vtile   (A = P from LDS, B = V from swizzled-transposed LDS)
        #pragma unroll
        for (int kp = 0; kp < 2; ++kp) {
            bf16x8 pa = __builtin_bit_cast(bf16x8,
                *reinterpret_cast<const uint4*>(&Ps[w][c][32 * kp + 8 * g]));
            #pragma unroll
            for (int t = 0; t < 4; ++t) {
                const int dv = 16 * t + c;
                const int pr = dv ^ ((2 * t + (c >> 3)) & 7);
                bf16x8 vf = __builtin_bit_cast(bf16x8,
                    *reinterpret_cast<const uint4*>(&Vt[pr][32 * kp + 8 * g]));
                o[t] = __builtin_amdgcn_mfma_f32_16x16x32_bf16(pa, vf, o[t], 0, 0, 0);
            }
        }
    }

    // epilogue: unnormalized partials
    const int rowbase = b * SS + q0 + 16 * w;
    #pragma unroll
    for (int t = 0; t < 4; ++t)
        #pragma unroll
        for (int i = 0; i < 4; ++i)
            Opart[((size_t)sp * NROW + rowbase + 4 * g + i) * DH + 16 * t + c] = o[t][i];
    if (c == 0) {
        #pragma unroll
        for (int i = 0; i < 4; ++i) {
            mpart[(size_t)sp * NROW + rowbase + 4 * g + i] = m_i[i];
            lpart[(size_t)sp * NROW + rowbase + 4 * g + i] = l_i[i];
        }
    }
}

// ---------------- combine partials ----------------
__global__ __launch_bounds__(256) void attn_combine(
    const float* __restrict__ Opart, const float* __restrict__ mpart,
    const float* __restrict__ lpart, float* __restrict__ out)
{
    const int idx = blockIdx.x * 256 + threadIdx.x;   // row*16 + d4
    const int row = idx >> 4;
    const int d4  = (idx & 15) * 4;

    float m[NS];
    float M = -1e30f;
    #pragma unroll
    for (int s = 0; s < NS; ++s) {
        m[s] = mpart[(size_t)s * NROW + row];
        M = fmaxf(M, m[s]);
    }
    float L = 0.f;
    float4 acc = {0.f, 0.f, 0.f, 0.f};
    #pragma unroll
    for (int s = 0; s < NS; ++s) {
        const float wgt = __expf(m[s] - M);
        L += wgt * lpart[(size_t)s * NROW + row];
        const float4 p = *reinterpret_cast<const float4*>(
            &Opart[((size_t)s * NROW + row) * DH + d4]);
        acc.x += wgt * p.x; acc.y += wgt * p.y;
        acc.z += wgt * p.z; acc.w += wgt * p.w;
    }
    const float inv = 1.f / L;
    float4 r = {acc.x * inv, acc.y * inv, acc.z * inv, acc.w * inv};
    *reinterpret_cast<float4*>(&out[(size_t)row * DH + d4]) = r;
}

extern "C" void kernel_launch(void* const* d_in, const int* in_sizes, int n_in,
                              void* d_out, int out_size, void* d_ws, size_t ws_size,
                              hipStream_t stream) {
    const float* emb = (const float*)d_in[0];
    const float* Wq  = (const float*)d_in[1];
    const float* bq  = (const float*)d_in[2];
    const float* Wk  = (const float*)d_in[3];
    const float* bk  = (const float*)d_in[4];
    const float* Wv  = (const float*)d_in[5];
    const float* bv  = (const float*)d_in[6];
    float* out = (float*)d_out;

    unsigned short* Qw = (unsigned short*)d_ws;
    unsigned short* Kw = Qw + (size_t)NROW * DH;
    unsigned short* Vw = Kw + (size_t)NROW * DH;
    unsigned short* Wt = Vw + (size_t)NROW * DH;          // 192*1024 bf16
    float* Opart = (float*)(Wt + (size_t)192 * DMODEL);   // [NS][NROW][DH] f32
    float* mpart = Opart + (size_t)NS * NROW * DH;        // [NS][NROW]
    float* lpart = mpart + (size_t)NS * NROW;             // [NS][NROW]

    hipLaunchKernelGGL(prep_wt_kernel, dim3(768), dim3(256), 0, stream,
                       Wq, Wk, Wv, Wt);
    hipLaunchKernelGGL(qkv_proj_mfma, dim3(NROW / 16), dim3(512), 0, stream,
                       emb, Wt, bq, bk, bv, Qw, Kw, Vw);
    hipLaunchKernelGGL(attn_mfma_split, dim3(SS / 64, BB, NS), dim3(256), 0, stream,
                       Qw, Kw, Vw, Opart, mpart, lpart);
    hipLaunchKernelGGL(attn_combine, dim3(NROW * 16 / 256), dim3(256), 0, stream,
                       Opart, mpart, lpart, out);
}

// Round 13
// 57.592 us; speedup vs baseline: 1.3337x; 1.0661x over previous
//
#include <hip/hip_runtime.h>
#include <hip/hip_bf16.h>

#define DMODEL 1024
#define DH 64
#define BB 4
#define SS 2048
#define NROW (BB * SS)   // 8192
#define NS 8             // kv-splits per q-tile

typedef __attribute__((ext_vector_type(8))) short bf16x8;
typedef __attribute__((ext_vector_type(4))) float f32x4;

__device__ __forceinline__ unsigned short f2bf(float f) {
    __hip_bfloat16 h = __float2bfloat16(f);
    return __builtin_bit_cast(unsigned short, h);
}

// ---------------- prep: Wt[192][1024] bf16 = [Wq|Wk|Wv]^T ----------------
__global__ __launch_bounds__(256) void prep_wt_kernel(
    const float* __restrict__ Wq, const float* __restrict__ Wk,
    const float* __restrict__ Wv, unsigned short* __restrict__ Wt)
{
    int idx = blockIdx.x * 256 + threadIdx.x;      // 0 .. 196607
    int m   = idx >> 16;                           // 0..2
    int rem = idx & 65535;
    int k   = rem >> 6;
    int n   = rem & 63;
    const float* W = (m == 0) ? Wq : (m == 1) ? Wk : Wv;
    float v = W[(size_t)k * DH + n];               // coalesced read
    Wt[(size_t)(m * 64 + n) * DMODEL + k] = f2bf(v);
}

// ---------------- QKV projection via MFMA, in-block K-split ----------------
// (unchanged from round 11 for clean A/B attribution)
__global__ __launch_bounds__(512) void qkv_proj_mfma(
    const float* __restrict__ emb, const unsigned short* __restrict__ Wt,
    const float* __restrict__ bq, const float* __restrict__ bk,
    const float* __restrict__ bv,
    unsigned short* __restrict__ Q, unsigned short* __restrict__ K,
    unsigned short* __restrict__ V)
{
    __shared__ unsigned short A_lds[2][16][264];   // 16 rows x 256 k (lo|hi)
    __shared__ float Red[4][16][48];               // high-half partial C

    const int tid  = threadIdx.x;
    const int lane = tid & 63;
    const int w    = tid >> 6;          // 0..7
    const int wc   = w & 3;             // col group (48 cols)
    const int h    = w >> 2;            // K half
    const int c    = lane & 15;
    const int g    = lane >> 4;
    const int row0 = blockIdx.x * 16;

    f32x4 acc[3];
    #pragma unroll
    for (int t = 0; t < 3; ++t) acc[t] = (f32x4){0.f, 0.f, 0.f, 0.f};

    const int sr0 = tid >> 6;                     // 0..7
    const int c4  = tid & 63;                     // 0..63
    const int gchunk = (c4 >> 5) ? 512 : 0;       // lo / hi K chunk
    const int coff   = (c4 & 31) * 4;
    const float* s0 = emb + (size_t)(row0 + sr0) * DMODEL + gchunk + coff;
    const float* s1 = emb + (size_t)(row0 + sr0 + 8) * DMODEL + gchunk + coff;

    float4 f0 = *reinterpret_cast<const float4*>(s0);
    float4 f1 = *reinterpret_cast<const float4*>(s1);

    const unsigned short* bbase =
        Wt + (size_t)(48 * wc + c) * DMODEL + h * 512 + 8 * g;

    for (int s = 0; s < 4; ++s) {
        const int buf = s & 1;
        {
            uint2 p0, p1;
            p0.x = (unsigned)f2bf(f0.x) | ((unsigned)f2bf(f0.y) << 16);
            p0.y = (unsigned)f2bf(f0.z) | ((unsigned)f2bf(f0.w) << 16);
            p1.x = (unsigned)f2bf(f1.x) | ((unsigned)f2bf(f1.y) << 16);
            p1.y = (unsigned)f2bf(f1.z) | ((unsigned)f2bf(f1.w) << 16);
            *reinterpret_cast<uint2*>(&A_lds[buf][sr0][c4 * 4])     = p0;
            *reinterpret_cast<uint2*>(&A_lds[buf][sr0 + 8][c4 * 4]) = p1;
        }
        if (s < 3) {   // loads for s+1 fly during this step's compute
            f0 = *reinterpret_cast<const float4*>(s0 + 128 * (s + 1));
            f1 = *reinterpret_cast<const float4*>(s1 + 128 * (s + 1));
        }
        __syncthreads();

        bf16x8 a[4];
        #pragma unroll
        for (int kp = 0; kp < 4; ++kp)
            a[kp] = __builtin_bit_cast(bf16x8,
                *reinterpret_cast<const uint4*>(
                    &A_lds[buf][c][128 * h + 32 * kp + 8 * g]));

        uint4 bf[3][4];
        #pragma unroll
        for (int t = 0; t < 3; ++t)
            #pragma unroll
            for (int kp = 0; kp < 4; ++kp)
                bf[t][kp] = *reinterpret_cast<const uint4*>(
                    bbase + (size_t)(16 * t) * DMODEL + 128 * s + 32 * kp);
        #pragma unroll
        for (int kp = 0; kp < 4; ++kp)
            #pragma unroll
            for (int t = 0; t < 3; ++t)
                acc[t] = __builtin_amdgcn_mfma_f32_16x16x32_bf16(
                    a[kp], __builtin_bit_cast(bf16x8, bf[t][kp]), acc[t], 0, 0, 0);
    }

    __syncthreads();
    if (h == 1) {
        #pragma unroll
        for (int t = 0; t < 3; ++t)
            #pragma unroll
            for (int i = 0; i < 4; ++i)
                Red[wc][4 * g + i][16 * t + c] = acc[t][i];
    }
    __syncthreads();
    if (h == 0) {
        #pragma unroll
        for (int t = 0; t < 3; ++t) {
            const int col = 48 * wc + 16 * t + c;
            const int m   = col >> 6;
            const int lc  = col & 63;
            const float* bias = (m == 0) ? bq : (m == 1) ? bk : bv;
            unsigned short* O = (m == 0) ? Q : (m == 1) ? K : V;
            const float bs    = bias[lc];
            const float scale = (m == 0) ? 0.125f : 1.0f;
            #pragma unroll
            for (int i = 0; i < 4; ++i) {
                const float v = acc[t][i] + Red[wc][4 * g + i][16 * t + c];
                const int r = row0 + 4 * g + i;
                O[(size_t)r * DH + lc] = f2bf((v + bs) * scale);
            }
        }
    }
}

// ---------------- causal flash attention via MFMA, KV-split ----------------
// SWAPPED-OPERAND QK^T: compute S^T = mfma(K,Q) so each lane owns one full
// q-row (q = 16w+c). Softmax: in-lane reduce + 2 shuffles (was 32). P^T packed
// to LDS as 4 x b64; PV = mfma(V^T, P^T) -> O^T; epilogue float4 stores.
__global__ __launch_bounds__(256) void attn_mfma_split(
    const unsigned short* __restrict__ Q, const unsigned short* __restrict__ K,
    const unsigned short* __restrict__ V,
    float* __restrict__ Opart, float* __restrict__ mpart,
    float* __restrict__ lpart)
{
    __shared__ unsigned short Ks[64][72];      // [kv][d]
    __shared__ unsigned short Vt[64][72];      // [phys_d][kv], row-swizzled
    __shared__ unsigned short Ps[4][16][72];   // per-wave P rows [q-local][kv]

    const int tid  = threadIdx.x;
    const int lane = tid & 63;
    const int w    = tid >> 6;
    const int c    = lane & 15;
    const int g    = lane >> 4;
    const int qt   = blockIdx.x;
    const int b    = blockIdx.y;
    const int sp   = blockIdx.z;
    const int q0   = qt * 64;

    const int ntile = qt + 1;
    const int kt0 = (ntile * sp) / NS;
    const int kt1 = (ntile * (sp + 1)) / NS;

    const unsigned short* Qb = Q + (size_t)b * SS * DH;
    const unsigned short* Kb = K + (size_t)b * SS * DH;
    const unsigned short* Vb = V + (size_t)b * SS * DH;

    // Q fragments, register resident (scale 1/8 already folded in)
    bf16x8 qa[2];
    #pragma unroll
    for (int kp = 0; kp < 2; ++kp)
        qa[kp] = __builtin_bit_cast(bf16x8,
            *reinterpret_cast<const uint4*>(
                &Qb[(size_t)(q0 + 16 * w + c) * DH + 32 * kp + 8 * g]));

    f32x4 o[4];   // o[t][i] = O^T[d = 16t+4g+i][q = 16w+c], unnormalized
    #pragma unroll
    for (int t = 0; t < 4; ++t) o[t] = (f32x4){0.f, 0.f, 0.f, 0.f};
    float m_i = -1e30f;
    float l_i = 0.f;

    for (int kt = kt0; kt < kt1; ++kt) {
        const int kb0 = kt * 64;
        __syncthreads();   // prior tile's LDS reads done
        // stage K (row-major) and V (transposed, row-swizzled)
        #pragma unroll
        for (int j = 0; j < 2; ++j) {
            const int idx = tid + 256 * j;
            const int kv  = idx >> 3;
            const int m8  = idx & 7;
            const int d0  = m8 * 8;
            *reinterpret_cast<uint4*>(&Ks[kv][d0]) =
                *reinterpret_cast<const uint4*>(&Kb[(size_t)(kb0 + kv) * DH + d0]);
            const uint4 vv =
                *reinterpret_cast<const uint4*>(&Vb[(size_t)(kb0 + kv) * DH + d0]);
            const unsigned wd[4] = {vv.x, vv.y, vv.z, vv.w};
            #pragma unroll
            for (int e = 0; e < 8; ++e)
                Vt[(d0 + e) ^ m8][kv] =
                    (unsigned short)(wd[e >> 1] >> (16 * (e & 1)));
        }
        __syncthreads();

        // S^T = Ktile . Q^T : s[t] lane(c,g) reg i = S[q=16w+c][kv=16t+4g+i]
        f32x4 s[4];
        #pragma unroll
        for (int t = 0; t < 4; ++t) s[t] = (f32x4){0.f, 0.f, 0.f, 0.f};
        #pragma unroll
        for (int t = 0; t < 4; ++t)
            #pragma unroll
            for (int kp = 0; kp < 2; ++kp) {
                bf16x8 kf = __builtin_bit_cast(bf16x8,
                    *reinterpret_cast<const uint4*>(&Ks[16 * t + c][32 * kp + 8 * g]));
                s[t] = __builtin_amdgcn_mfma_f32_16x16x32_bf16(kf, qa[kp], s[t], 0, 0, 0);
            }

        // causal mask (only the diagonal tile needs it): kv > q
        if (kt == qt) {
            #pragma unroll
            for (int t = 0; t < 4; ++t)
                #pragma unroll
                for (int i = 0; i < 4; ++i)
                    if (16 * t + 4 * g + i > 16 * w + c) s[t][i] = -1e30f;
        }

        // online softmax: lane owns q-row; partners at lane^16, lane^32
        float mx = m_i;
        #pragma unroll
        for (int t = 0; t < 4; ++t)
            mx = fmaxf(mx, fmaxf(fmaxf(s[t][0], s[t][1]), fmaxf(s[t][2], s[t][3])));
        mx = fmaxf(mx, __shfl_xor(mx, 16));
        mx = fmaxf(mx, __shfl_xor(mx, 32));
        const float al = __expf(m_i - mx);
        m_i = mx;
        float sum = 0.f;
        #pragma unroll
        for (int t = 0; t < 4; ++t)
            #pragma unroll
            for (int i = 0; i < 4; ++i) {
                const float p = __expf(s[t][i] - mx);
                s[t][i] = p;
                sum += p;
            }
        sum += __shfl_xor(sum, 16);
        sum += __shfl_xor(sum, 32);
        l_i = l_i * al + sum;

        // P^T pack -> Ps[w][q-local=c][kv]  (4 x b64)
        #pragma unroll
        for (int t = 0; t < 4; ++t) {
            uint2 u;
            u.x = (unsigned)f2bf(s[t][0]) | ((unsigned)f2bf(s[t][1]) << 16);
            u.y = (unsigned)f2bf(s[t][2]) | ((unsigned)f2bf(s[t][3]) << 16);
            *reinterpret_cast<uint2*>(&Ps[w][c][16 * t + 4 * g]) = u;
        }

        // rescale O
        #pragma unroll
        for (int t = 0; t < 4; ++t)
            #pragma unroll
            for (int i = 0; i < 4; ++i)
                o[t][i] *= al;

        // O^T += V^T . P^T   (A = V^T from swizzled LDS, B = P^T from Ps)
        #pragma unroll
        for (int kp = 0; kp < 2; ++kp) {
            bf16x8 pb = __builtin_bit_cast(bf16x8,
                *reinterpret_cast<const uint4*>(&Ps[w][c][32 * kp + 8 * g]));
            #pragma unroll
            for (int t = 0; t < 4; ++t) {
                const int dv = 16 * t + c;
                const int pr = dv ^ ((2 * t + (c >> 3)) & 7);
                bf16x8 vf = __builtin_bit_cast(bf16x8,
                    *reinterpret_cast<const uint4*>(&Vt[pr][32 * kp + 8 * g]));
                o[t] = __builtin_amdgcn_mfma_f32_16x16x32_bf16(vf, pb, o[t], 0, 0, 0);
            }
        }
    }

    // epilogue: unnormalized partials; lane owns q-row q0+16w+c, d = 16t+4g+i
    const int qrow = b * SS + q0 + 16 * w + c;
    #pragma unroll
    for (int t = 0; t < 4; ++t) {
        float4 v = {o[t][0], o[t][1], o[t][2], o[t][3]};
        *reinterpret_cast<float4*>(
            &Opart[((size_t)sp * NROW + qrow) * DH + 16 * t + 4 * g]) = v;
    }
    if (g == 0) {
        mpart[(size_t)sp * NROW + qrow] = m_i;
        lpart[(size_t)sp * NROW + qrow] = l_i;
    }
}

// ---------------- combine partials ----------------
__global__ __launch_bounds__(256) void attn_combine(
    const float* __restrict__ Opart, const float* __restrict__ mpart,
    const float* __restrict__ lpart, float* __restrict__ out)
{
    const int idx = blockIdx.x * 256 + threadIdx.x;   // row*16 + d4
    const int row = idx >> 4;
    const int d4  = (idx & 15) * 4;

    float m[NS];
    float M = -1e30f;
    #pragma unroll
    for (int s = 0; s < NS; ++s) {
        m[s] = mpart[(size_t)s * NROW + row];
        M = fmaxf(M, m[s]);
    }
    float L = 0.f;
    float4 acc = {0.f, 0.f, 0.f, 0.f};
    #pragma unroll
    for (int s = 0; s < NS; ++s) {
        const float wgt = __expf(m[s] - M);
        L += wgt * lpart[(size_t)s * NROW + row];
        const float4 p = *reinterpret_cast<const float4*>(
            &Opart[((size_t)s * NROW + row) * DH + d4]);
        acc.x += wgt * p.x; acc.y += wgt * p.y;
        acc.z += wgt * p.z; acc.w += wgt * p.w;
    }
    const float inv = 1.f / L;
    float4 r = {acc.x * inv, acc.y * inv, acc.z * inv, acc.w * inv};
    *reinterpret_cast<float4*>(&out[(size_t)row * DH + d4]) = r;
}

extern "C" void kernel_launch(void* const* d_in, const int* in_sizes, int n_in,
                              void* d_out, int out_size, void* d_ws, size_t ws_size,
                              hipStream_t stream) {
    const float* emb = (const float*)d_in[0];
    const float* Wq  = (const float*)d_in[1];
    const float* bq  = (const float*)d_in[2];
    const float* Wk  = (const float*)d_in[3];
    const float* bk  = (const float*)d_in[4];
    const float* Wv  = (const float*)d_in[5];
    const float* bv  = (const float*)d_in[6];
    float* out = (float*)d_out;

    unsigned short* Qw = (unsigned short*)d_ws;
    unsigned short* Kw = Qw + (size_t)NROW * DH;
    unsigned short* Vw = Kw + (size_t)NROW * DH;
    unsigned short* Wt = Vw + (size_t)NROW * DH;          // 192*1024 bf16
    float* Opart = (float*)(Wt + (size_t)192 * DMODEL);   // [NS][NROW][DH] f32
    float* mpart = Opart + (size_t)NS * NROW * DH;        // [NS][NROW]
    float* lpart = mpart + (size_t)NS * NROW;             // [NS][NROW]

    hipLaunchKernelGGL(prep_wt_kernel, dim3(768), dim3(256), 0, stream,
                       Wq, Wk, Wv, Wt);
    hipLaunchKernelGGL(qkv_proj_mfma, dim3(NROW / 16), dim3(512), 0, stream,
                       emb, Wt, bq, bk, bv, Qw, Kw, Vw);
    hipLaunchKernelGGL(attn_mfma_split, dim3(SS / 64, BB, NS), dim3(256), 0, stream,
                       Qw, Kw, Vw, Opart, mpart, lpart);
    hipLaunchKernelGGL(attn_combine, dim3(NROW * 16 / 256), dim3(256), 0, stream,
                       Opart, mpart, lpart, out);
}

// Round 14
// 54.070 us; speedup vs baseline: 1.4206x; 1.0651x over previous
//
#include <hip/hip_runtime.h>
#include <hip/hip_bf16.h>

#define DMODEL 1024
#define DH 64
#define BB 4
#define SS 2048
#define NROW (BB * SS)   // 8192
#define NS 8             // kv-splits per q-tile

typedef __attribute__((ext_vector_type(8))) short bf16x8;
typedef __attribute__((ext_vector_type(4))) float f32x4;

__device__ __forceinline__ unsigned short f2bf(float f) {
    __hip_bfloat16 h = __float2bfloat16(f);
    return __builtin_bit_cast(unsigned short, h);
}

// ---------------- prep: Wt[192][1024] bf16 = [Wq|Wk|Wv]^T ----------------
__global__ __launch_bounds__(256) void prep_wt_kernel(
    const float* __restrict__ Wq, const float* __restrict__ Wk,
    const float* __restrict__ Wv, unsigned short* __restrict__ Wt)
{
    int idx = blockIdx.x * 256 + threadIdx.x;      // 0 .. 196607
    int m   = idx >> 16;                           // 0..2
    int rem = idx & 65535;
    int k   = rem >> 6;
    int n   = rem & 63;
    const float* W = (m == 0) ? Wq : (m == 1) ? Wk : Wv;
    float v = W[(size_t)k * DH + n];               // coalesced read
    Wt[(size_t)(m * 64 + n) * DMODEL + k] = f2bf(v);
}

// ---------------- QKV projection: barrier-free, gll-staged B ----------------
// grid (256,2) x 256 thr. Block: 32 rows x 96 cols. Wave (wr,wc): 16 rows x
// 48 cols. B staged by global_load_lds into WAVE-PRIVATE LDS (3-deep ring,
// XOR-swizzled source), so the K-loop has NO barriers and loads stay in
// flight across steps; consume gated by counted s_waitcnt vmcnt(10).
__global__ __launch_bounds__(256) void qkv_proj_mfma(
    const float* __restrict__ emb, const unsigned short* __restrict__ Wt,
    const float* __restrict__ bq, const float* __restrict__ bk,
    const float* __restrict__ bv,
    unsigned short* __restrict__ Q, unsigned short* __restrict__ K,
    unsigned short* __restrict__ V)
{
    __shared__ unsigned short Bs[4][3][48 * 64];   // [wave][ring][48 rows x 64 bf16] = 72 KB

    const int tid  = threadIdx.x;
    const int lane = tid & 63;
    const int w    = tid >> 6;          // 0..3
    const int wr   = w >> 1;            // row half
    const int wc   = w & 1;             // col half
    const int c    = lane & 15;
    const int g    = lane >> 4;
    const int row0    = blockIdx.x * 32 + 16 * wr;
    const int colbase = blockIdx.y * 96 + 48 * wc;   // wave's 48-col slice

    // B gll source swizzle: inst j, lane i -> row colbase+8j+(i>>3),
    // slot (i&7)^((i>>3)&7). HW writes LDS at base + i*16 (linear).
    const int bj_row = lane >> 3;                        // 0..7
    const int bj_sl  = (lane & 7) ^ (bj_row & 7);        // pre-swizzled slot
    const unsigned short* wt_lane =
        Wt + (size_t)(colbase + bj_row) * DMODEL + 8 * bj_sl;

    // A: lane (c,g) reads row row0+c, fp32; per step floats 64s + {8g..8g+7, 32+8g..}
    const float* arow = emb + (size_t)(row0 + c) * DMODEL + 8 * g;

    f32x4 acc[3];
    #pragma unroll
    for (int t = 0; t < 3; ++t) acc[t] = (f32x4){0.f, 0.f, 0.f, 0.f};

    float4 a0[3], a1[3], a2[3], a3[3];   // 3-slot A ring (static-indexed)

#define ISSUE(S, R) do {                                                     \
    _Pragma("unroll")                                                        \
    for (int j = 0; j < 6; ++j)                                              \
        __builtin_amdgcn_global_load_lds(                                    \
            (const __attribute__((address_space(1))) void*)(                 \
                wt_lane + (size_t)8 * (j) * DMODEL + 64 * (S)),              \
            (__attribute__((address_space(3))) void*)&Bs[w][R][(j) * 512],   \
            16, 0, 0);                                                       \
    a0[R] = *reinterpret_cast<const float4*>(arow + 64 * (S));               \
    a1[R] = *reinterpret_cast<const float4*>(arow + 64 * (S) + 4);           \
    a2[R] = *reinterpret_cast<const float4*>(arow + 64 * (S) + 32);          \
    a3[R] = *reinterpret_cast<const float4*>(arow + 64 * (S) + 36);          \
} while (0)

    ISSUE(0, 0);
    ISSUE(1, 1);

    #pragma unroll
    for (int s = 0; s < 16; ++s) {
        const int r = s % 3;
        // retire step s (10 vmem ops/step; newest 10 = step s+1 may stay)
        if (s < 15) asm volatile("s_waitcnt vmcnt(10)" ::: "memory");
        else        asm volatile("s_waitcnt vmcnt(0)"  ::: "memory");
        __builtin_amdgcn_sched_barrier(0);

        if (s + 2 < 16) ISSUE(s + 2, (s + 2) % 3);

        // A fragments: fp32 -> bf16
        bf16x8 af[2];
        {
            union { bf16x8 v; unsigned short u[8]; } p0, p1;
            p0.u[0] = f2bf(a0[r].x); p0.u[1] = f2bf(a0[r].y);
            p0.u[2] = f2bf(a0[r].z); p0.u[3] = f2bf(a0[r].w);
            p0.u[4] = f2bf(a1[r].x); p0.u[5] = f2bf(a1[r].y);
            p0.u[6] = f2bf(a1[r].z); p0.u[7] = f2bf(a1[r].w);
            p1.u[0] = f2bf(a2[r].x); p1.u[1] = f2bf(a2[r].y);
            p1.u[2] = f2bf(a2[r].z); p1.u[3] = f2bf(a2[r].w);
            p1.u[4] = f2bf(a3[r].x); p1.u[5] = f2bf(a3[r].y);
            p1.u[6] = f2bf(a3[r].z); p1.u[7] = f2bf(a3[r].w);
            af[0] = p0.v; af[1] = p1.v;
        }

        // B fragments from wave-private LDS (same XOR involution) + MFMA
        #pragma unroll
        for (int t = 0; t < 3; ++t)
            #pragma unroll
            for (int kp = 0; kp < 2; ++kp) {
                const int lrow = 16 * t + c;
                const int slot = (4 * kp + g) ^ (lrow & 7);
                bf16x8 bfr = __builtin_bit_cast(bf16x8,
                    *reinterpret_cast<const uint4*>(&Bs[w][r][lrow * 64 + slot * 8]));
                acc[t] = __builtin_amdgcn_mfma_f32_16x16x32_bf16(af[kp], bfr, acc[t], 0, 0, 0);
            }
    }
#undef ISSUE

    // epilogue: bias (+ 1/8 scale folded into Q), store bf16
    #pragma unroll
    for (int t = 0; t < 3; ++t) {
        const int col = colbase + 16 * t + c;
        const int m   = col >> 6;
        const int lc  = col & 63;
        const float* bias = (m == 0) ? bq : (m == 1) ? bk : bv;
        unsigned short* O = (m == 0) ? Q : (m == 1) ? K : V;
        const float bs    = bias[lc];
        const float scale = (m == 0) ? 0.125f : 1.0f;
        #pragma unroll
        for (int i = 0; i < 4; ++i) {
            const int rr = row0 + 4 * g + i;
            O[(size_t)rr * DH + lc] = f2bf((acc[t][i] + bs) * scale);
        }
    }
}

// ---------------- causal flash attention via MFMA, KV-split ----------------
// (unchanged from round 13)
__global__ __launch_bounds__(256) void attn_mfma_split(
    const unsigned short* __restrict__ Q, const unsigned short* __restrict__ K,
    const unsigned short* __restrict__ V,
    float* __restrict__ Opart, float* __restrict__ mpart,
    float* __restrict__ lpart)
{
    __shared__ unsigned short Ks[64][72];      // [kv][d]
    __shared__ unsigned short Vt[64][72];      // [phys_d][kv], row-swizzled
    __shared__ unsigned short Ps[4][16][72];   // per-wave P rows [q-local][kv]

    const int tid  = threadIdx.x;
    const int lane = tid & 63;
    const int w    = tid >> 6;
    const int c    = lane & 15;
    const int g    = lane >> 4;
    const int qt   = blockIdx.x;
    const int b    = blockIdx.y;
    const int sp   = blockIdx.z;
    const int q0   = qt * 64;

    const int ntile = qt + 1;
    const int kt0 = (ntile * sp) / NS;
    const int kt1 = (ntile * (sp + 1)) / NS;

    const unsigned short* Qb = Q + (size_t)b * SS * DH;
    const unsigned short* Kb = K + (size_t)b * SS * DH;
    const unsigned short* Vb = V + (size_t)b * SS * DH;

    bf16x8 qa[2];
    #pragma unroll
    for (int kp = 0; kp < 2; ++kp)
        qa[kp] = __builtin_bit_cast(bf16x8,
            *reinterpret_cast<const uint4*>(
                &Qb[(size_t)(q0 + 16 * w + c) * DH + 32 * kp + 8 * g]));

    f32x4 o[4];   // o[t][i] = O^T[d = 16t+4g+i][q = 16w+c], unnormalized
    #pragma unroll
    for (int t = 0; t < 4; ++t) o[t] = (f32x4){0.f, 0.f, 0.f, 0.f};
    float m_i = -1e30f;
    float l_i = 0.f;

    for (int kt = kt0; kt < kt1; ++kt) {
        const int kb0 = kt * 64;
        __syncthreads();
        #pragma unroll
        for (int j = 0; j < 2; ++j) {
            const int idx = tid + 256 * j;
            const int kv  = idx >> 3;
            const int m8  = idx & 7;
            const int d0  = m8 * 8;
            *reinterpret_cast<uint4*>(&Ks[kv][d0]) =
                *reinterpret_cast<const uint4*>(&Kb[(size_t)(kb0 + kv) * DH + d0]);
            const uint4 vv =
                *reinterpret_cast<const uint4*>(&Vb[(size_t)(kb0 + kv) * DH + d0]);
            const unsigned wd[4] = {vv.x, vv.y, vv.z, vv.w};
            #pragma unroll
            for (int e = 0; e < 8; ++e)
                Vt[(d0 + e) ^ m8][kv] =
                    (unsigned short)(wd[e >> 1] >> (16 * (e & 1)));
        }
        __syncthreads();

        f32x4 s[4];
        #pragma unroll
        for (int t = 0; t < 4; ++t) s[t] = (f32x4){0.f, 0.f, 0.f, 0.f};
        #pragma unroll
        for (int t = 0; t < 4; ++t)
            #pragma unroll
            for (int kp = 0; kp < 2; ++kp) {
                bf16x8 kf = __builtin_bit_cast(bf16x8,
                    *reinterpret_cast<const uint4*>(&Ks[16 * t + c][32 * kp + 8 * g]));
                s[t] = __builtin_amdgcn_mfma_f32_16x16x32_bf16(kf, qa[kp], s[t], 0, 0, 0);
            }

        if (kt == qt) {
            #pragma unroll
            for (int t = 0; t < 4; ++t)
                #pragma unroll
                for (int i = 0; i < 4; ++i)
                    if (16 * t + 4 * g + i > 16 * w + c) s[t][i] = -1e30f;
        }

        float mx = m_i;
        #pragma unroll
        for (int t = 0; t < 4; ++t)
            mx = fmaxf(mx, fmaxf(fmaxf(s[t][0], s[t][1]), fmaxf(s[t][2], s[t][3])));
        mx = fmaxf(mx, __shfl_xor(mx, 16));
        mx = fmaxf(mx, __shfl_xor(mx, 32));
        const float al = __expf(m_i - mx);
        m_i = mx;
        float sum = 0.f;
        #pragma unroll
        for (int t = 0; t < 4; ++t)
            #pragma unroll
            for (int i = 0; i < 4; ++i) {
                const float p = __expf(s[t][i] - mx);
                s[t][i] = p;
                sum += p;
            }
        sum += __shfl_xor(sum, 16);
        sum += __shfl_xor(sum, 32);
        l_i = l_i * al + sum;

        #pragma unroll
        for (int t = 0; t < 4; ++t) {
            uint2 u;
            u.x = (unsigned)f2bf(s[t][0]) | ((unsigned)f2bf(s[t][1]) << 16);
            u.y = (unsigned)f2bf(s[t][2]) | ((unsigned)f2bf(s[t][3]) << 16);
            *reinterpret_cast<uint2*>(&Ps[w][c][16 * t + 4 * g]) = u;
        }

        #pragma unroll
        for (int t = 0; t < 4; ++t)
            #pragma unroll
            for (int i = 0; i < 4; ++i)
                o[t][i] *= al;

        #pragma unroll
        for (int kp = 0; kp < 2; ++kp) {
            bf16x8 pb = __builtin_bit_cast(bf16x8,
                *reinterpret_cast<const uint4*>(&Ps[w][c][32 * kp + 8 * g]));
            #pragma unroll
            for (int t = 0; t < 4; ++t) {
                const int dv = 16 * t + c;
                const int pr = dv ^ ((2 * t + (c >> 3)) & 7);
                bf16x8 vf = __builtin_bit_cast(bf16x8,
                    *reinterpret_cast<const uint4*>(&Vt[pr][32 * kp + 8 * g]));
                o[t] = __builtin_amdgcn_mfma_f32_16x16x32_bf16(vf, pb, o[t], 0, 0, 0);
            }
        }
    }

    const int qrow = b * SS + q0 + 16 * w + c;
    #pragma unroll
    for (int t = 0; t < 4; ++t) {
        float4 v = {o[t][0], o[t][1], o[t][2], o[t][3]};
        *reinterpret_cast<float4*>(
            &Opart[((size_t)sp * NROW + qrow) * DH + 16 * t + 4 * g]) = v;
    }
    if (g == 0) {
        mpart[(size_t)sp * NROW + qrow] = m_i;
        lpart[(size_t)sp * NROW + qrow] = l_i;
    }
}

// ---------------- combine partials ----------------
__global__ __launch_bounds__(256) void attn_combine(
    const float* __restrict__ Opart, const float* __restrict__ mpart,
    const float* __restrict__ lpart, float* __restrict__ out)
{
    const int idx = blockIdx.x * 256 + threadIdx.x;   // row*16 + d4
    const int row = idx >> 4;
    const int d4  = (idx & 15) * 4;

    float m[NS];
    float M = -1e30f;
    #pragma unroll
    for (int s = 0; s < NS; ++s) {
        m[s] = mpart[(size_t)s * NROW + row];
        M = fmaxf(M, m[s]);
    }
    float L = 0.f;
    float4 acc = {0.f, 0.f, 0.f, 0.f};
    #pragma unroll
    for (int s = 0; s < NS; ++s) {
        const float wgt = __expf(m[s] - M);
        L += wgt * lpart[(size_t)s * NROW + row];
        const float4 p = *reinterpret_cast<const float4*>(
            &Opart[((size_t)s * NROW + row) * DH + d4]);
        acc.x += wgt * p.x; acc.y += wgt * p.y;
        acc.z += wgt * p.z; acc.w += wgt * p.w;
    }
    const float inv = 1.f / L;
    float4 r = {acc.x * inv, acc.y * inv, acc.z * inv, acc.w * inv};
    *reinterpret_cast<float4*>(&out[(size_t)row * DH + d4]) = r;
}

extern "C" void kernel_launch(void* const* d_in, const int* in_sizes, int n_in,
                              void* d_out, int out_size, void* d_ws, size_t ws_size,
                              hipStream_t stream) {
    const float* emb = (const float*)d_in[0];
    const float* Wq  = (const float*)d_in[1];
    const float* bq  = (const float*)d_in[2];
    const float* Wk  = (const float*)d_in[3];
    const float* bk  = (const float*)d_in[4];
    const float* Wv  = (const float*)d_in[5];
    const float* bv  = (const float*)d_in[6];
    float* out = (float*)d_out;

    unsigned short* Qw = (unsigned short*)d_ws;
    unsigned short* Kw = Qw + (size_t)NROW * DH;
    unsigned short* Vw = Kw + (size_t)NROW * DH;
    unsigned short* Wt = Vw + (size_t)NROW * DH;          // 192*1024 bf16
    float* Opart = (float*)(Wt + (size_t)192 * DMODEL);   // [NS][NROW][DH] f32
    float* mpart = Opart + (size_t)NS * NROW * DH;        // [NS][NROW]
    float* lpart = mpart + (size_t)NS * NROW;             // [NS][NROW]

    hipLaunchKernelGGL(prep_wt_kernel, dim3(768), dim3(256), 0, stream,
                       Wq, Wk, Wv, Wt);
    hipLaunchKernelGGL(qkv_proj_mfma, dim3(NROW / 32, 2), dim3(256), 0, stream,
                       emb, Wt, bq, bk, bv, Qw, Kw, Vw);
    hipLaunchKernelGGL(attn_mfma_split, dim3(SS / 64, BB, NS), dim3(256), 0, stream,
                       Qw, Kw, Vw, Opart, mpart, lpart);
    hipLaunchKernelGGL(attn_combine, dim3(NROW * 16 / 256), dim3(256), 0, stream,
                       Opart, mpart, lpart, out);
}